// Round 10
// baseline (354.469 us; speedup 1.0000x reference)
//
#include <hip/hip_runtime.h>

// Attention_6219112645023 — fp32 in / fp32 out, bf16 internal compute (MFMA).
// B=2, T=2048, DIM=2048, NH=32, NKV=8, HD=64. Causal GQA + RoPE + projections.
// Pipeline: cvt5 -> qkv_gemm -> transpose(V) -> flash attn -> O gemm.
// R8/R9: attn — swapped QK^T + slot permutation + reg pipeline + setprio.
// R11: GEMM 128x128/BK=64 4-wave DBUF, XOR swizzle (conflicts=0).
// R13: counted vmcnt (never drain in loop); attn K/V dbuf, 1 barrier/kt.
// R14 lesson: GEMM B global->reg = L2 thrash (no cross-wave reuse). REVERTED.
// R15 lesson: splitting prefetch halves hiding distance, -18%. REVERTED.
// R16: 2-D L2-aware XCD regions (FETCH 108->59 MB; time-neutral -> latency
//      was already hidden; qkv is LDS-port + MFMA bound). KEPT.
// R17: attn K operand global->REGISTER direct. Unlike the GEMM (R14), attn's
// K-frags are IDENTICAL across the 4 waves and the tile is 8 KB: quads
// complete 64B/row, h2 halves complete the 128B line, 4 waves x 4 blocks
// (same kvh) hit L1. Removes K's ds_write + 4x-redundant ds_read: attn LDS
// traffic -50%, Ks buffer freed. V path + barrier structure unchanged.

typedef unsigned short u16;
typedef __attribute__((ext_vector_type(8))) short bf16x8;  // 8 bf16 in 4 VGPRs
typedef __attribute__((ext_vector_type(4))) float f32x4;
typedef __attribute__((ext_vector_type(4))) unsigned short u16x4;

constexpr int T_SEQ = 2048;
constexpr int DIMC  = 2048;
constexpr int NHEAD = 32;
constexpr int HDIM  = 64;
constexpr int KVDIM = 512;   // NKV * HDIM
constexpr int BATCH = 2;

__device__ __forceinline__ u16 f2bf(float f) {
    union { float f; unsigned int i; } v; v.f = f;
    unsigned int r = v.i + 0x7FFFu + ((v.i >> 16) & 1u);   // RNE
    return (u16)(r >> 16);
}

// pack two f32 -> (bf16 lo = e0, bf16 hi = e1), truncating (P in [0,1]).
__device__ __forceinline__ unsigned int pack2_bf16(float e0, float e1) {
    return __builtin_amdgcn_perm(__float_as_uint(e1), __float_as_uint(e0),
                                 0x07060302u);
}

typedef __attribute__((address_space(1))) unsigned int as1_uint;
typedef __attribute__((address_space(3))) unsigned int as3_uint;
__device__ __forceinline__ void glds16(const u16* g, u16* l) {
    // async global->LDS, 16B/lane; LDS dest = wave-uniform base + lane*16
    __builtin_amdgcn_global_load_lds((as1_uint*)(u16*)g, (as3_uint*)l, 16, 0, 0);
}

// ===========================================================================
// Fused fp32->bf16 convert of all 5 inputs (one launch).
// ===========================================================================
__global__ __launch_bounds__(256) void cvt5(const float* __restrict__ x,
                                            const float* __restrict__ wq,
                                            const float* __restrict__ wk,
                                            const float* __restrict__ wv,
                                            const float* __restrict__ wo,
                                            u16* __restrict__ xb,  u16* __restrict__ wqb,
                                            u16* __restrict__ wkb, u16* __restrict__ wvb,
                                            u16* __restrict__ wob) {
    constexpr int E0 = BATCH * T_SEQ * DIMC;          // 8388608
    constexpr int E1 = E0 + DIMC * DIMC;              // +4194304
    constexpr int E2 = E1 + KVDIM * DIMC;             // +1048576
    constexpr int E3 = E2 + KVDIM * DIMC;             // +1048576
    constexpr int E4 = E3 + DIMC * DIMC;              // 18874368 total
    for (int i = (blockIdx.x * 256 + threadIdx.x) * 4; i < E4; i += gridDim.x * 1024) {
        const float* s; u16* d; int off;
        if (i < E0)      { s = x;  d = xb;  off = 0;  }
        else if (i < E1) { s = wq; d = wqb; off = E0; }
        else if (i < E2) { s = wk; d = wkb; off = E1; }
        else if (i < E3) { s = wv; d = wvb; off = E2; }
        else             { s = wo; d = wob; off = E3; }
        f32x4 v = *(const f32x4*)(s + (i - off));
        u16x4 o;
        #pragma unroll
        for (int e = 0; e < 4; ++e) o[e] = f2bf(v[e]);
        *(u16x4*)(d + (i - off)) = o;
    }
}

// ===========================================================================
// DBUF GEMM core (R13 schedule): C = A[M][K] . W[N][K]^T, 128x128 tile,
// BK=64, 256 threads (4 waves 2x2; per-wave 64x64 = acc[4][4]).
// LDS: 2 bufs x (A 128x64 + B 128x64) = 64 KiB -> 2 blocks/CU.
// Swizzle (conflicts=0 proven): logical (row,col) at LDS elem
//   row*64 + (col ^ ((row&7)*8)); glds SOURCE col pre-swizzled (linear dest).
// Per K-tile: s_barrier (cb^1 reads retired) -> issue ALL 8 glds t+1 ->
// vmcnt(8) (t's 8 done, t+1's 8 FLYING a full tile ahead) -> s_barrier ->
// 16 ds_read_b128 + 32 MFMA. Never drains to 0 in the loop.
// ===========================================================================
template <bool OUTF32>
__device__ __forceinline__ void dgemm_core(const u16* __restrict__ A,
                                           const u16* __restrict__ W,
                                           void* __restrict__ Cv,
                                           int rowBase, int colBase,
                                           int N, int K, bool rope) {
    __shared__ __align__(16) u16 Ash[2][128 * 64];   // 32 KiB
    __shared__ __align__(16) u16 Bsh[2][128 * 64];   // 32 KiB

    const int tid  = threadIdx.x;
    const int lane = tid & 63;
    const int w    = tid >> 6;           // 0..3
    const int quad = lane >> 4;
    const int ln   = lane & 15;
    const int wm   = (w >> 1) * 64;
    const int wn   = (w & 1) * 64;

    const int sr = lane >> 3;            // 0..7
    const int sc = 8 * ((lane & 7) ^ sr);
    const u16* aS = A + (size_t)(rowBase + w * 8 + sr) * K + sc;
    const u16* bS = W + (size_t)(colBase + w * 8 + sr) * K + sc;

    f32x4 acc[4][4] = {};
    const int NT = K / 64;
    const int swz = (ln & 7) * 8;

    // prologue: stage tile 0 -> buf 0 (8 glds/thread)
    #pragma unroll
    for (int r = 0; r < 4; ++r) {
        glds16(aS + (size_t)(r * 32) * K, &Ash[0][(w + 4 * r) * 512]);
        glds16(bS + (size_t)(r * 32) * K, &Bsh[0][(w + 4 * r) * 512]);
    }

    for (int t = 0; t < NT; ++t) {
        const int cb = t & 1;
        __builtin_amdgcn_s_barrier();          // reads of buf cb^1 complete
        __builtin_amdgcn_sched_barrier(0);

        if (t + 1 < NT) {
            const size_t ko = (size_t)(t + 1) * 64;
            u16* An = &Ash[cb ^ 1][0];
            u16* Bn = &Bsh[cb ^ 1][0];
            #pragma unroll
            for (int r = 0; r < 4; ++r) {
                glds16(aS + ko + (size_t)(r * 32) * K, An + (w + 4 * r) * 512);
                glds16(bS + ko + (size_t)(r * 32) * K, Bn + (w + 4 * r) * 512);
            }
            __builtin_amdgcn_sched_barrier(0);
            __asm__ __volatile__("s_waitcnt vmcnt(8)" ::: "memory");  // t done, t+1 flying
        } else {
            __asm__ __volatile__("s_waitcnt vmcnt(0)" ::: "memory");  // epilogue drain
        }
        __builtin_amdgcn_sched_barrier(0);
        __builtin_amdgcn_s_barrier();          // tile t published

        const u16* Ap = &Ash[cb][0];
        const u16* Bp = &Bsh[cb][0];
        #pragma unroll
        for (int q2 = 0; q2 < 2; ++q2) {
            bf16x8 bwf[4];
            #pragma unroll
            for (int n = 0; n < 4; ++n)
                bwf[n] = *(const bf16x8*)(Bp + (wn + n * 16 + ln) * 64
                                             + ((q2 * 32 + quad * 8) ^ swz));
            __builtin_amdgcn_s_setprio(1);
            #pragma unroll
            for (int m = 0; m < 4; ++m) {
                bf16x8 af = *(const bf16x8*)(Ap + (wm + m * 16 + ln) * 64
                                                + ((q2 * 32 + quad * 8) ^ swz));
                #pragma unroll
                for (int n = 0; n < 4; ++n)
                    acc[m][n] = __builtin_amdgcn_mfma_f32_16x16x32_bf16(af, bwf[n], acc[m][n], 0, 0, 0);
            }
            __builtin_amdgcn_s_setprio(0);
        }
    }

    if (rope) {
        // head-local d = j*16+ln; pairs (d, d+32) -> (acc[i][j], acc[i][j+2]).
        #pragma unroll
        for (int j = 0; j < 2; ++j) {
            const int d = j * 16 + ln;
            const float invrev = exp2f(-(float)d * (13.287712379549449f / 32.0f))
                                 * 0.15915494309189535f;   // /2pi
            #pragma unroll
            for (int i = 0; i < 4; ++i) {
                #pragma unroll
                for (int r = 0; r < 4; ++r) {
                    const int t = (rowBase + wm + i * 16 + quad * 4 + r) & (T_SEQ - 1);
                    float rev = (float)t * invrev;
                    float fr = rev - floorf(rev);
                    float sn = __builtin_amdgcn_sinf(fr);
                    float cs = __builtin_amdgcn_cosf(fr);
                    float a0 = acc[i][j][r], a2 = acc[i][j + 2][r];
                    acc[i][j][r]     = a0 * cs - a2 * sn;
                    acc[i][j + 2][r] = a2 * cs + a0 * sn;
                }
            }
        }
    }

    #pragma unroll
    for (int i = 0; i < 4; ++i) {
        int mrow = rowBase + wm + i * 16 + quad * 4;
        #pragma unroll
        for (int j = 0; j < 4; ++j) {
            int n = colBase + wn + j * 16 + ln;
            #pragma unroll
            for (int r = 0; r < 4; ++r) {
                if constexpr (OUTF32)
                    ((float*)Cv)[(size_t)(mrow + r) * N + n] = acc[i][j][r];
                else
                    ((u16*)Cv)[(size_t)(mrow + r) * N + n] = f2bf(acc[i][j][r]);
            }
        }
    }
}

// Fused QKV: 24 col-tiles (Q 16 | K 4 | V 4) x 32 row-tiles = 768 blocks.
// R16 XCD region: each XCD owns 16 rows x 6 cols (96 blocks), col-fast.
__global__ __launch_bounds__(256, 2) void qkv_gemm(const u16* __restrict__ xb,
                                                   const u16* __restrict__ wqb,
                                                   const u16* __restrict__ wkb,
                                                   const u16* __restrict__ wvb,
                                                   u16* __restrict__ Qb,
                                                   u16* __restrict__ Kb,
                                                   u16* __restrict__ Vb) {
    const int flat = blockIdx.y * 24 + blockIdx.x;
    const int xcd  = flat & 7;
    const int idx  = flat >> 3;          // 0..95
    const int row  = (xcd >> 2) * 16 + idx / 6;
    const int ct   = (xcd & 3) * 6 + idx % 6;
    const int rowBase = row * 128;

    const u16* W; u16* C; int colBase, N; bool rope;
    if (ct < 16)      { W = wqb; C = Qb; colBase = ct * 128;        N = DIMC;  rope = true; }
    else if (ct < 20) { W = wkb; C = Kb; colBase = (ct - 16) * 128; N = KVDIM; rope = true; }
    else              { W = wvb; C = Vb; colBase = (ct - 20) * 128; N = KVDIM; rope = false; }
    dgemm_core<false>(xb, W, C, rowBase, colBase, N, DIMC, rope);
}

// O-projection: 16 col-tiles x 32 row-tiles = 512 blocks.
// R16 XCD region: 16 rows x 4 cols per XCD (W slab 2 MB L2-resident).
__global__ __launch_bounds__(256, 2) void gemm_out(const u16* __restrict__ A,
                                                   const u16* __restrict__ W,
                                                   float* __restrict__ C) {
    const int flat = blockIdx.y * 16 + blockIdx.x;
    const int xcd  = flat & 7;
    const int idx  = flat >> 3;          // 0..63
    const int row  = (xcd >> 2) * 16 + (idx >> 2);
    const int col  = (xcd & 3) * 4 + (idx & 3);
    dgemm_core<true>(A, W, C, row * 128, col * 128, DIMC, DIMC, false);
}

// ===========================================================================
// V [B*T][KVDIM] -> Vt [B][KVDIM][T]
// ===========================================================================
__global__ __launch_bounds__(256) void transpose_v(const u16* __restrict__ V,
                                                   u16* __restrict__ Vt) {
    __shared__ __align__(16) u16 tile[32][33];
    const int x = threadIdx.x & 31;
    const int y = threadIdx.x >> 5;
    const int tok0 = blockIdx.y * 32;
    const int c0   = blockIdx.x * 32;
    #pragma unroll
    for (int yy = 0; yy < 32; yy += 8)
        tile[y + yy][x] = V[(size_t)(tok0 + y + yy) * KVDIM + c0 + x];
    __syncthreads();
    const int b  = tok0 >> 11;
    const int t0 = tok0 & (T_SEQ - 1);
    #pragma unroll
    for (int yy = 0; yy < 32; yy += 8)
        Vt[(size_t)(b * KVDIM + c0 + y + yy) * T_SEQ + t0 + x] = tile[x][y + yy];
}

// ===========================================================================
// Flash attention. grid = (16, NH, B), block = 256 (4 waves).
// R8: swapped QK^T (D[key][q]) + key->slot permutation
//   slot(k) = 32*(k>>5) + 8*((k>>2)&3) + 4*((k>>4)&1) + (k&3)
// R9: T14 async-STAGE reg pipeline (V) + T5 setprio.
// R13: V double-buffered LDS -> ONE raw barrier per kt.
// R17: K operand global->register direct (no K LDS at all). Per lane
// 8 x 16B loads: rows st*16+ln (stride 1 KB), cols h2*32+quad*8. Quads
// complete 64B per row, h2 halves complete the 128B line, 4 waves + 4
// co-resident blocks (same kvh) repeat the same 8 KB tile -> L1 hits.
// Loads issued at iteration top; V-write + lgkm + barrier window hides
// their latency before the first QK MFMA consumes them.
// ===========================================================================
__global__ __launch_bounds__(256) void attn(const u16* __restrict__ Q,
                                            const u16* __restrict__ Kx,
                                            const u16* __restrict__ Vt,
                                            u16* __restrict__ O) {
    __shared__ __align__(16) u16 Vs[2][64][72];    // [buf][dim][slot]

    const int tid  = threadIdx.x;
    const int lane = tid & 63;
    const int w    = tid >> 6;
    const int quad = lane >> 4;
    const int ln   = lane & 15;
    const int h    = blockIdx.y;
    const int b    = blockIdx.z;
    const int kvh  = h >> 2;

    const int srow = tid >> 2;           // 0..63
    const int c    = tid & 3;
    const int scol = c * 16;             // token group base (16 tokens)
    const int vsb  = 32 * (c >> 1) + 4 * (c & 1);
    // K direct-read lane base: row ln (stride KVDIM), col quad*8
    const u16* kLane = Kx + (size_t)(b * T_SEQ + ln) * KVDIM + kvh * HDIM + quad * 8;
    const u16* vbase = Vt + (size_t)(b * KVDIM + kvh * HDIM + srow) * T_SEQ;

    const float K1 = 0.125f * 1.4426950408889634f;   // scale * log2(e)
    const float K2 = 8.0f * 1.4426950408889634f;     // M0 * log2(e)

    #pragma unroll
    for (int phase = 0; phase < 2; ++phase) {
        const int qt = phase ? (31 - (int)blockIdx.x) : (int)blockIdx.x;
        const int qr0 = qt * 64 + w * 16;

        const u16* qp = Q + (size_t)(b * T_SEQ + qr0 + ln) * DIMC + h * HDIM + quad * 8;
        const bf16x8 bq0 = *(const bf16x8*)qp;        // B-operand: col = q = ln
        const bf16x8 bq1 = *(const bf16x8*)(qp + 32);

        f32x4 o[4] = {};
        float lsum = 0.0f;

        // pipeline prologue: V tile-0 staging loads into registers
        bf16x8 vra = *(const bf16x8*)(vbase + scol);
        bf16x8 vrb = *(const bf16x8*)(vbase + scol + 8);

        for (int kt = 0; kt <= qt; ++kt) {
            const int cb = kt & 1;
            const size_t krow = (size_t)kt * 64 * KVDIM;

            // K frags for THIS tile, global->reg (8 x 16B/lane, L1-shared).
            // kf[st][h2] = K[k0 + st*16 + ln][kvh*64 + h2*32 + quad*8 ..+7]
            bf16x8 kf0a = *(const bf16x8*)(kLane + krow);
            bf16x8 kf0b = *(const bf16x8*)(kLane + krow + 32);
            bf16x8 kf1a = *(const bf16x8*)(kLane + krow + (size_t)16 * KVDIM);
            bf16x8 kf1b = *(const bf16x8*)(kLane + krow + (size_t)16 * KVDIM + 32);
            bf16x8 kf2a = *(const bf16x8*)(kLane + krow + (size_t)32 * KVDIM);
            bf16x8 kf2b = *(const bf16x8*)(kLane + krow + (size_t)32 * KVDIM + 32);
            bf16x8 kf3a = *(const bf16x8*)(kLane + krow + (size_t)48 * KVDIM);
            bf16x8 kf3b = *(const bf16x8*)(kLane + krow + (size_t)48 * KVDIM + 32);

            {   // V staging, slot-permuted: 4x ds_write_b64
                union { bf16x8 v; u16x4 h4[2]; } ua, ub;
                ua.v = vra; ub.v = vrb;
                *(u16x4*)&Vs[cb][srow][vsb]      = ua.h4[0];
                *(u16x4*)&Vs[cb][srow][vsb + 8]  = ua.h4[1];
                *(u16x4*)&Vs[cb][srow][vsb + 16] = ub.h4[0];
                *(u16x4*)&Vs[cb][srow][vsb + 24] = ub.h4[1];
            }

            // prefetch V tile kt+1 into regs — flies under this tile's compute
            if (kt < qt) {
                const size_t ko = (size_t)(kt + 1) * 64;
                vra = *(const bf16x8*)(vbase + ko + scol);
                vrb = *(const bf16x8*)(vbase + ko + scol + 8);
            }

            // own LDS writes (and prior reads) drained, then ONE raw barrier
            __asm__ __volatile__("s_waitcnt lgkmcnt(0)" ::: "memory");
            __builtin_amdgcn_s_barrier();

            // QK^T swapped: D[key][q]; K from registers (vmcnt waits auto)
            f32x4 s[4];
            __builtin_amdgcn_s_setprio(1);
            {
                f32x4 z0 = {}, z1 = {}, z2 = {}, z3 = {};
                s[0] = __builtin_amdgcn_mfma_f32_16x16x32_bf16(kf0a, bq0, z0, 0, 0, 0);
                s[0] = __builtin_amdgcn_mfma_f32_16x16x32_bf16(kf0b, bq1, s[0], 0, 0, 0);
                s[1] = __builtin_amdgcn_mfma_f32_16x16x32_bf16(kf1a, bq0, z1, 0, 0, 0);
                s[1] = __builtin_amdgcn_mfma_f32_16x16x32_bf16(kf1b, bq1, s[1], 0, 0, 0);
                s[2] = __builtin_amdgcn_mfma_f32_16x16x32_bf16(kf2a, bq0, z2, 0, 0, 0);
                s[2] = __builtin_amdgcn_mfma_f32_16x16x32_bf16(kf2b, bq1, s[2], 0, 0, 0);
                s[3] = __builtin_amdgcn_mfma_f32_16x16x32_bf16(kf3a, bq0, z3, 0, 0, 0);
                s[3] = __builtin_amdgcn_mfma_f32_16x16x32_bf16(kf3b, bq1, s[3], 0, 0, 0);
            }
            __builtin_amdgcn_s_setprio(0);

            unsigned int pk[8];
            if (kt != qt) {
                #pragma unroll
                for (int st = 0; st < 4; ++st) {
                    float e0 = exp2f(fmaf(s[st][0], K1, -K2));
                    float e1 = exp2f(fmaf(s[st][1], K1, -K2));
                    float e2 = exp2f(fmaf(s[st][2], K1, -K2));
                    float e3 = exp2f(fmaf(s[st][3], K1, -K2));
                    lsum += (e0 + e1) + (e2 + e3);
                    pk[2 * st]     = pack2_bf16(e0, e1);
                    pk[2 * st + 1] = pack2_bf16(e2, e3);
                }
            } else {
                const int thr = w * 16 + ln;            // q local in 64-block
                #pragma unroll
                for (int st = 0; st < 4; ++st) {
                    float e[4];
                    #pragma unroll
                    for (int r = 0; r < 4; ++r) {
                        const int key = st * 16 + quad * 4 + r;
                        e[r] = (key > thr) ? 0.0f : exp2f(fmaf(s[st][r], K1, -K2));
                    }
                    lsum += (e[0] + e[1]) + (e[2] + e[3]);
                    pk[2 * st]     = pack2_bf16(e[0], e[1]);
                    pk[2 * st + 1] = pack2_bf16(e[2], e[3]);
                }
            }

            union { unsigned int u[4]; bf16x8 v; } a0, a1;
            a0.u[0] = pk[0]; a0.u[1] = pk[1]; a0.u[2] = pk[2]; a0.u[3] = pk[3];
            a1.u[0] = pk[4]; a1.u[1] = pk[5]; a1.u[2] = pk[6]; a1.u[3] = pk[7];

            __builtin_amdgcn_s_setprio(1);
            #pragma unroll
            for (int t = 0; t < 4; ++t) {
                o[t] = __builtin_amdgcn_mfma_f32_16x16x32_bf16(
                           a0.v, *(const bf16x8*)&Vs[cb][t * 16 + ln][quad * 8], o[t], 0, 0, 0);
                o[t] = __builtin_amdgcn_mfma_f32_16x16x32_bf16(
                           a1.v, *(const bf16x8*)&Vs[cb][t * 16 + ln][32 + quad * 8], o[t], 0, 0, 0);
            }
            __builtin_amdgcn_s_setprio(0);
        }

        float ls = lsum;
        ls += __shfl_xor(ls, 16);
        ls += __shfl_xor(ls, 32);
        #pragma unroll
        for (int r = 0; r < 4; ++r) {
            const float inv = 1.0f / __shfl(ls, quad * 4 + r);
            size_t obase = (size_t)(b * T_SEQ + qr0 + quad * 4 + r) * DIMC + h * HDIM;
            #pragma unroll
            for (int t = 0; t < 4; ++t)
                O[obase + t * 16 + ln] = f2bf(o[t][r] * inv);
        }

        // phase boundary: next phase's first ds_writes must not race
        // this phase's last ds_reads on slow waves.
        __syncthreads();
    }
}

// ===========================================================================
extern "C" void kernel_launch(void* const* d_in, const int* in_sizes, int n_in,
                              void* d_out, int out_size, void* d_ws, size_t ws_size,
                              hipStream_t stream) {
    const float* x  = (const float*)d_in[0];
    const float* wq = (const float*)d_in[1];
    const float* wk = (const float*)d_in[2];
    const float* wv = (const float*)d_in[3];
    const float* wo = (const float*)d_in[4];
    float* out = (float*)d_out;

    char* ws = (char*)d_ws;
    constexpr size_t MB = 1024 * 1024;
    u16* Qb  = (u16*)(ws);             // 16 MB [4096][2048]
    u16* Kb  = (u16*)(ws + 16 * MB);   //  4 MB [4096][512]
    u16* Vb  = (u16*)(ws + 20 * MB);   //  4 MB [4096][512]
    u16* Vtb = (u16*)(ws + 24 * MB);   //  4 MB [2][512][2048]
    u16* AOb = (u16*)(ws + 28 * MB);   // 16 MB [4096][2048]  (aliases xb)
    u16* xb  = AOb;                    // x dead before attn writes AOb
    u16* wqb = (u16*)(ws + 44 * MB);   //  8 MB
    u16* wkb = (u16*)(ws + 52 * MB);   //  2 MB
    u16* wvb = (u16*)(ws + 54 * MB);   //  2 MB
    u16* wob = (u16*)(ws + 56 * MB);   //  8 MB
    const int M = BATCH * T_SEQ;       // 4096

    hipLaunchKernelGGL(cvt5, dim3(2048), dim3(256), 0, stream,
                       x, wq, wk, wv, wo, xb, wqb, wkb, wvb, wob);
    hipLaunchKernelGGL(qkv_gemm, dim3(24, M / 128), dim3(256), 0, stream,
                       xb, wqb, wkb, wvb, Qb, Kb, Vb);
    hipLaunchKernelGGL(transpose_v, dim3(KVDIM / 32, M / 32), dim3(256), 0, stream, Vb, Vtb);
    hipLaunchKernelGGL(attn, dim3(16, NHEAD, BATCH), dim3(256), 0, stream,
                       Qb, Kb, Vtb, AOb);
    hipLaunchKernelGGL(gemm_out, dim3(DIMC / 128, M / 128), dim3(256), 0, stream,
                       AOb, wob, out);
}

// Round 11
// 288.861 us; speedup vs baseline: 1.2271x; 1.2271x over previous
//
#include <hip/hip_runtime.h>

// Attention_6219112645023 — fp32 in / fp32 out, bf16 internal compute (MFMA).
// B=2, T=2048, DIM=2048, NH=32, NKV=8, HD=64. Causal GQA + RoPE + projections.
// Pipeline: cvt5 -> qkv_gemm -> transpose(V) -> flash attn -> O gemm.
// R11: GEMM 128x128/BK=64 4-wave DBUF, XOR swizzle (conflicts=0).
// R13: counted vmcnt (never drain in loop); attn K/V dbuf, 1 barrier/kt.
// R14/R17 lesson: global->reg operand fetch only works when a wave's lanes
//   cover whole cache lines; 1KB-row-stride 16B/lane = 16 txn/instr. REVERTED.
// R15 lesson: splitting prefetch halves hiding distance. REVERTED.
// R16: 2-D L2-aware XCD regions (FETCH -45%). KEPT.
// R18: attn arithmetic-intensity x2 — each wave owns TWO 16-row q-groups
// (Q-block 128, grid 8x32x2 = 512, paired qt/(15-qt) -> uniform 34 kt).
// Every K/V fragment is ds_read ONCE and feeds TWO MFMAs (one per group):
// LDS traffic per FLOP halves (~10.6 -> ~5.4 MB/CU). Sync skeleton = R13.
// Masking: kdiff = kt-(2qt+g); full if <0 else thr = w*16+ln-64*kdiff.

typedef unsigned short u16;
typedef __attribute__((ext_vector_type(8))) short bf16x8;  // 8 bf16 in 4 VGPRs
typedef __attribute__((ext_vector_type(4))) float f32x4;
typedef __attribute__((ext_vector_type(4))) unsigned short u16x4;

constexpr int T_SEQ = 2048;
constexpr int DIMC  = 2048;
constexpr int NHEAD = 32;
constexpr int HDIM  = 64;
constexpr int KVDIM = 512;   // NKV * HDIM
constexpr int BATCH = 2;

__device__ __forceinline__ u16 f2bf(float f) {
    union { float f; unsigned int i; } v; v.f = f;
    unsigned int r = v.i + 0x7FFFu + ((v.i >> 16) & 1u);   // RNE
    return (u16)(r >> 16);
}

// pack two f32 -> (bf16 lo = e0, bf16 hi = e1), truncating (P in [0,1]).
__device__ __forceinline__ unsigned int pack2_bf16(float e0, float e1) {
    return __builtin_amdgcn_perm(__float_as_uint(e1), __float_as_uint(e0),
                                 0x07060302u);
}

typedef __attribute__((address_space(1))) unsigned int as1_uint;
typedef __attribute__((address_space(3))) unsigned int as3_uint;
__device__ __forceinline__ void glds16(const u16* g, u16* l) {
    // async global->LDS, 16B/lane; LDS dest = wave-uniform base + lane*16
    __builtin_amdgcn_global_load_lds((as1_uint*)(u16*)g, (as3_uint*)l, 16, 0, 0);
}

// ===========================================================================
// Fused fp32->bf16 convert of all 5 inputs (one launch).
// ===========================================================================
__global__ __launch_bounds__(256) void cvt5(const float* __restrict__ x,
                                            const float* __restrict__ wq,
                                            const float* __restrict__ wk,
                                            const float* __restrict__ wv,
                                            const float* __restrict__ wo,
                                            u16* __restrict__ xb,  u16* __restrict__ wqb,
                                            u16* __restrict__ wkb, u16* __restrict__ wvb,
                                            u16* __restrict__ wob) {
    constexpr int E0 = BATCH * T_SEQ * DIMC;          // 8388608
    constexpr int E1 = E0 + DIMC * DIMC;              // +4194304
    constexpr int E2 = E1 + KVDIM * DIMC;             // +1048576
    constexpr int E3 = E2 + KVDIM * DIMC;             // +1048576
    constexpr int E4 = E3 + DIMC * DIMC;              // 18874368 total
    for (int i = (blockIdx.x * 256 + threadIdx.x) * 4; i < E4; i += gridDim.x * 1024) {
        const float* s; u16* d; int off;
        if (i < E0)      { s = x;  d = xb;  off = 0;  }
        else if (i < E1) { s = wq; d = wqb; off = E0; }
        else if (i < E2) { s = wk; d = wkb; off = E1; }
        else if (i < E3) { s = wv; d = wvb; off = E2; }
        else             { s = wo; d = wob; off = E3; }
        f32x4 v = *(const f32x4*)(s + (i - off));
        u16x4 o;
        #pragma unroll
        for (int e = 0; e < 4; ++e) o[e] = f2bf(v[e]);
        *(u16x4*)(d + (i - off)) = o;
    }
}

// ===========================================================================
// DBUF GEMM core (R13 schedule): C = A[M][K] . W[N][K]^T, 128x128 tile,
// BK=64, 256 threads (4 waves 2x2; per-wave 64x64 = acc[4][4]).
// LDS: 2 bufs x (A 128x64 + B 128x64) = 64 KiB -> 2 blocks/CU.
// Swizzle (conflicts=0 proven): logical (row,col) at LDS elem
//   row*64 + (col ^ ((row&7)*8)); glds SOURCE col pre-swizzled (linear dest).
// Per K-tile: s_barrier (cb^1 reads retired) -> issue ALL 8 glds t+1 ->
// vmcnt(8) (t's 8 done, t+1's 8 FLYING a full tile ahead) -> s_barrier ->
// 16 ds_read_b128 + 32 MFMA. Never drains to 0 in the loop.
// ===========================================================================
template <bool OUTF32>
__device__ __forceinline__ void dgemm_core(const u16* __restrict__ A,
                                           const u16* __restrict__ W,
                                           void* __restrict__ Cv,
                                           int rowBase, int colBase,
                                           int N, int K, bool rope) {
    __shared__ __align__(16) u16 Ash[2][128 * 64];   // 32 KiB
    __shared__ __align__(16) u16 Bsh[2][128 * 64];   // 32 KiB

    const int tid  = threadIdx.x;
    const int lane = tid & 63;
    const int w    = tid >> 6;           // 0..3
    const int quad = lane >> 4;
    const int ln   = lane & 15;
    const int wm   = (w >> 1) * 64;
    const int wn   = (w & 1) * 64;

    const int sr = lane >> 3;            // 0..7
    const int sc = 8 * ((lane & 7) ^ sr);
    const u16* aS = A + (size_t)(rowBase + w * 8 + sr) * K + sc;
    const u16* bS = W + (size_t)(colBase + w * 8 + sr) * K + sc;

    f32x4 acc[4][4] = {};
    const int NT = K / 64;
    const int swz = (ln & 7) * 8;

    // prologue: stage tile 0 -> buf 0 (8 glds/thread)
    #pragma unroll
    for (int r = 0; r < 4; ++r) {
        glds16(aS + (size_t)(r * 32) * K, &Ash[0][(w + 4 * r) * 512]);
        glds16(bS + (size_t)(r * 32) * K, &Bsh[0][(w + 4 * r) * 512]);
    }

    for (int t = 0; t < NT; ++t) {
        const int cb = t & 1;
        __builtin_amdgcn_s_barrier();          // reads of buf cb^1 complete
        __builtin_amdgcn_sched_barrier(0);

        if (t + 1 < NT) {
            const size_t ko = (size_t)(t + 1) * 64;
            u16* An = &Ash[cb ^ 1][0];
            u16* Bn = &Bsh[cb ^ 1][0];
            #pragma unroll
            for (int r = 0; r < 4; ++r) {
                glds16(aS + ko + (size_t)(r * 32) * K, An + (w + 4 * r) * 512);
                glds16(bS + ko + (size_t)(r * 32) * K, Bn + (w + 4 * r) * 512);
            }
            __builtin_amdgcn_sched_barrier(0);
            __asm__ __volatile__("s_waitcnt vmcnt(8)" ::: "memory");  // t done, t+1 flying
        } else {
            __asm__ __volatile__("s_waitcnt vmcnt(0)" ::: "memory");  // epilogue drain
        }
        __builtin_amdgcn_sched_barrier(0);
        __builtin_amdgcn_s_barrier();          // tile t published

        const u16* Ap = &Ash[cb][0];
        const u16* Bp = &Bsh[cb][0];
        #pragma unroll
        for (int q2 = 0; q2 < 2; ++q2) {
            bf16x8 bwf[4];
            #pragma unroll
            for (int n = 0; n < 4; ++n)
                bwf[n] = *(const bf16x8*)(Bp + (wn + n * 16 + ln) * 64
                                             + ((q2 * 32 + quad * 8) ^ swz));
            __builtin_amdgcn_s_setprio(1);
            #pragma unroll
            for (int m = 0; m < 4; ++m) {
                bf16x8 af = *(const bf16x8*)(Ap + (wm + m * 16 + ln) * 64
                                                + ((q2 * 32 + quad * 8) ^ swz));
                #pragma unroll
                for (int n = 0; n < 4; ++n)
                    acc[m][n] = __builtin_amdgcn_mfma_f32_16x16x32_bf16(af, bwf[n], acc[m][n], 0, 0, 0);
            }
            __builtin_amdgcn_s_setprio(0);
        }
    }

    if (rope) {
        // head-local d = j*16+ln; pairs (d, d+32) -> (acc[i][j], acc[i][j+2]).
        #pragma unroll
        for (int j = 0; j < 2; ++j) {
            const int d = j * 16 + ln;
            const float invrev = exp2f(-(float)d * (13.287712379549449f / 32.0f))
                                 * 0.15915494309189535f;   // /2pi
            #pragma unroll
            for (int i = 0; i < 4; ++i) {
                #pragma unroll
                for (int r = 0; r < 4; ++r) {
                    const int t = (rowBase + wm + i * 16 + quad * 4 + r) & (T_SEQ - 1);
                    float rev = (float)t * invrev;
                    float fr = rev - floorf(rev);
                    float sn = __builtin_amdgcn_sinf(fr);
                    float cs = __builtin_amdgcn_cosf(fr);
                    float a0 = acc[i][j][r], a2 = acc[i][j + 2][r];
                    acc[i][j][r]     = a0 * cs - a2 * sn;
                    acc[i][j + 2][r] = a2 * cs + a0 * sn;
                }
            }
        }
    }

    #pragma unroll
    for (int i = 0; i < 4; ++i) {
        int mrow = rowBase + wm + i * 16 + quad * 4;
        #pragma unroll
        for (int j = 0; j < 4; ++j) {
            int n = colBase + wn + j * 16 + ln;
            #pragma unroll
            for (int r = 0; r < 4; ++r) {
                if constexpr (OUTF32)
                    ((float*)Cv)[(size_t)(mrow + r) * N + n] = acc[i][j][r];
                else
                    ((u16*)Cv)[(size_t)(mrow + r) * N + n] = f2bf(acc[i][j][r]);
            }
        }
    }
}

// Fused QKV: 24 col-tiles (Q 16 | K 4 | V 4) x 32 row-tiles = 768 blocks.
// R16 XCD region: each XCD owns 16 rows x 6 cols (96 blocks), col-fast.
__global__ __launch_bounds__(256, 2) void qkv_gemm(const u16* __restrict__ xb,
                                                   const u16* __restrict__ wqb,
                                                   const u16* __restrict__ wkb,
                                                   const u16* __restrict__ wvb,
                                                   u16* __restrict__ Qb,
                                                   u16* __restrict__ Kb,
                                                   u16* __restrict__ Vb) {
    const int flat = blockIdx.y * 24 + blockIdx.x;
    const int xcd  = flat & 7;
    const int idx  = flat >> 3;          // 0..95
    const int row  = (xcd >> 2) * 16 + idx / 6;
    const int ct   = (xcd & 3) * 6 + idx % 6;
    const int rowBase = row * 128;

    const u16* W; u16* C; int colBase, N; bool rope;
    if (ct < 16)      { W = wqb; C = Qb; colBase = ct * 128;        N = DIMC;  rope = true; }
    else if (ct < 20) { W = wkb; C = Kb; colBase = (ct - 16) * 128; N = KVDIM; rope = true; }
    else              { W = wvb; C = Vb; colBase = (ct - 20) * 128; N = KVDIM; rope = false; }
    dgemm_core<false>(xb, W, C, rowBase, colBase, N, DIMC, rope);
}

// O-projection: 16 col-tiles x 32 row-tiles = 512 blocks.
// R16 XCD region: 16 rows x 4 cols per XCD (W slab 2 MB L2-resident).
__global__ __launch_bounds__(256, 2) void gemm_out(const u16* __restrict__ A,
                                                   const u16* __restrict__ W,
                                                   float* __restrict__ C) {
    const int flat = blockIdx.y * 16 + blockIdx.x;
    const int xcd  = flat & 7;
    const int idx  = flat >> 3;          // 0..63
    const int row  = (xcd >> 2) * 16 + (idx >> 2);
    const int col  = (xcd & 3) * 4 + (idx & 3);
    dgemm_core<true>(A, W, C, row * 128, col * 128, DIMC, DIMC, false);
}

// ===========================================================================
// V [B*T][KVDIM] -> Vt [B][KVDIM][T]
// ===========================================================================
__global__ __launch_bounds__(256) void transpose_v(const u16* __restrict__ V,
                                                   u16* __restrict__ Vt) {
    __shared__ __align__(16) u16 tile[32][33];
    const int x = threadIdx.x & 31;
    const int y = threadIdx.x >> 5;
    const int tok0 = blockIdx.y * 32;
    const int c0   = blockIdx.x * 32;
    #pragma unroll
    for (int yy = 0; yy < 32; yy += 8)
        tile[y + yy][x] = V[(size_t)(tok0 + y + yy) * KVDIM + c0 + x];
    __syncthreads();
    const int b  = tok0 >> 11;
    const int t0 = tok0 & (T_SEQ - 1);
    #pragma unroll
    for (int yy = 0; yy < 32; yy += 8)
        Vt[(size_t)(b * KVDIM + c0 + y + yy) * T_SEQ + t0 + x] = tile[x][y + yy];
}

// ===========================================================================
// Flash attention. grid = (8, NH, B), block = 256 (4 waves).
// R8: swapped QK^T (D[key][q]) + key->slot permutation
//   slot(k) = 32*(k>>5) + 8*((k>>2)&3) + 4*((k>>4)&1) + (k&3)
// R9/R13: reg-prefetch staging, K/V dbuf LDS, ONE raw barrier per kt.
// R18: Q-block 128 rows; each wave owns TWO 16-row q-groups (g=0: +w*16,
// g=1: +64+w*16). Each K/V frag is ds_read once and feeds both groups'
// MFMAs -> LDS reads per FLOP halve. Blocks pair qt and (15-qt): uniform
// (2qt+2) + (2(15-qt)+2) = 34 kt-tiles. Masking: kdiff = kt-(2qt+g);
// full if kdiff<0, else thr = w*16+ln-64*kdiff (kdiff=1 -> all masked).
// ===========================================================================
__global__ __launch_bounds__(256) void attn(const u16* __restrict__ Q,
                                            const u16* __restrict__ Kx,
                                            const u16* __restrict__ Vt,
                                            u16* __restrict__ O) {
    __shared__ __align__(16) u16 Ks[2][64][72];    // [buf][key][dim]
    __shared__ __align__(16) u16 Vs[2][64][72];    // [buf][dim][slot]

    const int tid  = threadIdx.x;
    const int lane = tid & 63;
    const int w    = tid >> 6;
    const int quad = lane >> 4;
    const int ln   = lane & 15;
    const int h    = blockIdx.y;
    const int b    = blockIdx.z;
    const int kvh  = h >> 2;

    const int srow = tid >> 2;           // 0..63
    const int c    = tid & 3;
    const int scol = c * 16;             // token group base (16 tokens)
    const int vsb  = 32 * (c >> 1) + 4 * (c & 1);
    const u16* kbase = Kx + (size_t)(b * T_SEQ + srow) * KVDIM + kvh * HDIM + scol;
    const u16* vbase = Vt + (size_t)(b * KVDIM + kvh * HDIM + srow) * T_SEQ;

    const float K1 = 0.125f * 1.4426950408889634f;   // scale * log2(e)
    const float K2 = 8.0f * 1.4426950408889634f;     // M0 * log2(e)

    #pragma unroll
    for (int phase = 0; phase < 2; ++phase) {
        const int qt = phase ? (15 - (int)blockIdx.x) : (int)blockIdx.x;
        const int qr0 = qt * 128 + w * 16;           // group 0; group 1 = +64

        const u16* qp0 = Q + (size_t)(b * T_SEQ + qr0 + ln) * DIMC + h * HDIM + quad * 8;
        const u16* qp1 = qp0 + (size_t)64 * DIMC;
        const bf16x8 bq00 = *(const bf16x8*)qp0;     // group 0, dims 0..31
        const bf16x8 bq01 = *(const bf16x8*)(qp0 + 32);
        const bf16x8 bq10 = *(const bf16x8*)qp1;     // group 1
        const bf16x8 bq11 = *(const bf16x8*)(qp1 + 32);

        f32x4 o0[4] = {}, o1[4] = {};
        float ls0 = 0.0f, ls1 = 0.0f;

        // pipeline prologue: tile-0 staging loads into registers
        bf16x8 kra = *(const bf16x8*)kbase;
        bf16x8 krb = *(const bf16x8*)(kbase + 8);
        bf16x8 vra = *(const bf16x8*)(vbase + scol);
        bf16x8 vrb = *(const bf16x8*)(vbase + scol + 8);

        const int NTk = 2 * qt + 2;
        for (int kt = 0; kt < NTk; ++kt) {
            const int cb = kt & 1;

            *(bf16x8*)&Ks[cb][srow][scol]     = kra;
            *(bf16x8*)&Ks[cb][srow][scol + 8] = krb;
            {   // V staging, slot-permuted: 4x ds_write_b64
                union { bf16x8 v; u16x4 h4[2]; } ua, ub;
                ua.v = vra; ub.v = vrb;
                *(u16x4*)&Vs[cb][srow][vsb]      = ua.h4[0];
                *(u16x4*)&Vs[cb][srow][vsb + 8]  = ua.h4[1];
                *(u16x4*)&Vs[cb][srow][vsb + 16] = ub.h4[0];
                *(u16x4*)&Vs[cb][srow][vsb + 24] = ub.h4[1];
            }

            // prefetch tile kt+1 into regs — flies under this tile's compute
            if (kt + 1 < NTk) {
                const size_t ko = (size_t)(kt + 1) * 64;
                kra = *(const bf16x8*)(kbase + ko * KVDIM);
                krb = *(const bf16x8*)(kbase + ko * KVDIM + 8);
                vra = *(const bf16x8*)(vbase + ko + scol);
                vrb = *(const bf16x8*)(vbase + ko + scol + 8);
            }

            // own LDS writes (and prior reads) drained, then ONE raw barrier
            __asm__ __volatile__("s_waitcnt lgkmcnt(0)" ::: "memory");
            __builtin_amdgcn_s_barrier();

            // QK^T swapped, both groups share each K frag (read once)
            f32x4 s0[4], s1[4];
            __builtin_amdgcn_s_setprio(1);
            #pragma unroll
            for (int st = 0; st < 4; ++st) {
                bf16x8 kfa = *(const bf16x8*)&Ks[cb][st * 16 + ln][quad * 8];
                bf16x8 kfb = *(const bf16x8*)&Ks[cb][st * 16 + ln][32 + quad * 8];
                f32x4 z0 = {}, z1 = {};
                s0[st] = __builtin_amdgcn_mfma_f32_16x16x32_bf16(kfa, bq00, z0, 0, 0, 0);
                s1[st] = __builtin_amdgcn_mfma_f32_16x16x32_bf16(kfa, bq10, z1, 0, 0, 0);
                s0[st] = __builtin_amdgcn_mfma_f32_16x16x32_bf16(kfb, bq01, s0[st], 0, 0, 0);
                s1[st] = __builtin_amdgcn_mfma_f32_16x16x32_bf16(kfb, bq11, s1[st], 0, 0, 0);
            }
            __builtin_amdgcn_s_setprio(0);

            // softmax numerator + pack, per group (kdiff = kt - (2qt+g))
            unsigned int pk0[8], pk1[8];
            #pragma unroll
            for (int g = 0; g < 2; ++g) {
                const f32x4* s = g ? s1 : s0;
                unsigned int* pk = g ? pk1 : pk0;
                float lsum = 0.0f;
                const int kdiff = kt - (2 * qt + g);
                if (kdiff < 0) {
                    #pragma unroll
                    for (int st = 0; st < 4; ++st) {
                        float e0 = exp2f(fmaf(s[st][0], K1, -K2));
                        float e1 = exp2f(fmaf(s[st][1], K1, -K2));
                        float e2 = exp2f(fmaf(s[st][2], K1, -K2));
                        float e3 = exp2f(fmaf(s[st][3], K1, -K2));
                        lsum += (e0 + e1) + (e2 + e3);
                        pk[2 * st]     = pack2_bf16(e0, e1);
                        pk[2 * st + 1] = pack2_bf16(e2, e3);
                    }
                } else {
                    const int thr = w * 16 + ln - 64 * kdiff;  // kdiff=1: all masked
                    #pragma unroll
                    for (int st = 0; st < 4; ++st) {
                        float e[4];
                        #pragma unroll
                        for (int r = 0; r < 4; ++r) {
                            const int key = st * 16 + quad * 4 + r;
                            e[r] = (key > thr) ? 0.0f : exp2f(fmaf(s[st][r], K1, -K2));
                        }
                        lsum += (e[0] + e[1]) + (e[2] + e[3]);
                        pk[2 * st]     = pack2_bf16(e[0], e[1]);
                        pk[2 * st + 1] = pack2_bf16(e[2], e[3]);
                    }
                }
                if (g) ls1 += lsum; else ls0 += lsum;
            }

            union { unsigned int u[4]; bf16x8 v; } a00, a01, a10, a11;
            a00.u[0] = pk0[0]; a00.u[1] = pk0[1]; a00.u[2] = pk0[2]; a00.u[3] = pk0[3];
            a01.u[0] = pk0[4]; a01.u[1] = pk0[5]; a01.u[2] = pk0[6]; a01.u[3] = pk0[7];
            a10.u[0] = pk1[0]; a10.u[1] = pk1[1]; a10.u[2] = pk1[2]; a10.u[3] = pk1[3];
            a11.u[0] = pk1[4]; a11.u[1] = pk1[5]; a11.u[2] = pk1[6]; a11.u[3] = pk1[7];

            // PV: each V frag read once, feeds both groups
            __builtin_amdgcn_s_setprio(1);
            #pragma unroll
            for (int t = 0; t < 4; ++t) {
                bf16x8 vfa = *(const bf16x8*)&Vs[cb][t * 16 + ln][quad * 8];
                bf16x8 vfb = *(const bf16x8*)&Vs[cb][t * 16 + ln][32 + quad * 8];
                o0[t] = __builtin_amdgcn_mfma_f32_16x16x32_bf16(a00.v, vfa, o0[t], 0, 0, 0);
                o1[t] = __builtin_amdgcn_mfma_f32_16x16x32_bf16(a10.v, vfa, o1[t], 0, 0, 0);
                o0[t] = __builtin_amdgcn_mfma_f32_16x16x32_bf16(a01.v, vfb, o0[t], 0, 0, 0);
                o1[t] = __builtin_amdgcn_mfma_f32_16x16x32_bf16(a11.v, vfb, o1[t], 0, 0, 0);
            }
            __builtin_amdgcn_s_setprio(0);
        }

        // epilogue per group: lsum is per-lane (q = ln); reduce across quads,
        // redistribute to O layout (q = quad*4+r held at col ln).
        #pragma unroll
        for (int g = 0; g < 2; ++g) {
            float ls = g ? ls1 : ls0;
            const f32x4* o = g ? o1 : o0;
            ls += __shfl_xor(ls, 16);
            ls += __shfl_xor(ls, 32);
            #pragma unroll
            for (int r = 0; r < 4; ++r) {
                const float inv = 1.0f / __shfl(ls, quad * 4 + r);
                size_t obase = (size_t)(b * T_SEQ + qr0 + g * 64 + quad * 4 + r) * DIMC
                               + h * HDIM;
                #pragma unroll
                for (int t = 0; t < 4; ++t)
                    O[obase + t * 16 + ln] = f2bf(o[t][r] * inv);
            }
        }

        // phase boundary: next phase's first ds_writes must not race
        // this phase's last ds_reads on slow waves.
        __syncthreads();
    }
}

// ===========================================================================
extern "C" void kernel_launch(void* const* d_in, const int* in_sizes, int n_in,
                              void* d_out, int out_size, void* d_ws, size_t ws_size,
                              hipStream_t stream) {
    const float* x  = (const float*)d_in[0];
    const float* wq = (const float*)d_in[1];
    const float* wk = (const float*)d_in[2];
    const float* wv = (const float*)d_in[3];
    const float* wo = (const float*)d_in[4];
    float* out = (float*)d_out;

    char* ws = (char*)d_ws;
    constexpr size_t MB = 1024 * 1024;
    u16* Qb  = (u16*)(ws);             // 16 MB [4096][2048]
    u16* Kb  = (u16*)(ws + 16 * MB);   //  4 MB [4096][512]
    u16* Vb  = (u16*)(ws + 20 * MB);   //  4 MB [4096][512]
    u16* Vtb = (u16*)(ws + 24 * MB);   //  4 MB [2][512][2048]
    u16* AOb = (u16*)(ws + 28 * MB);   // 16 MB [4096][2048]  (aliases xb)
    u16* xb  = AOb;                    // x dead before attn writes AOb
    u16* wqb = (u16*)(ws + 44 * MB);   //  8 MB
    u16* wkb = (u16*)(ws + 52 * MB);   //  2 MB
    u16* wvb = (u16*)(ws + 54 * MB);   //  2 MB
    u16* wob = (u16*)(ws + 56 * MB);   //  8 MB
    const int M = BATCH * T_SEQ;       // 4096

    hipLaunchKernelGGL(cvt5, dim3(2048), dim3(256), 0, stream,
                       x, wq, wk, wv, wo, xb, wqb, wkb, wvb, wob);
    hipLaunchKernelGGL(qkv_gemm, dim3(24, M / 128), dim3(256), 0, stream,
                       xb, wqb, wkb, wvb, Qb, Kb, Vb);
    hipLaunchKernelGGL(transpose_v, dim3(KVDIM / 32, M / 32), dim3(256), 0, stream, Vb, Vtb);
    hipLaunchKernelGGL(attn, dim3(8, NHEAD, BATCH), dim3(256), 0, stream,
                       Qb, Kb, Vtb, AOb);
    hipLaunchKernelGGL(gemm_out, dim3(DIMC / 128, M / 128), dim3(256), 0, stream,
                       AOb, wob, out);
}